// Round 9
// baseline (225.533 us; speedup 1.0000x reference)
//
#include <hip/hip_runtime.h>
#include <hip/hip_bf16.h>
#include <cstddef>

#define NBMAX 512     // max buckets (256 nodes each -> supports nN <= 131072)
#define BCAP 5120     // per-bucket edge capacity; mean ~4092, sigma ~64
#define BKCHUNK 6400  // max edges per bucket-sort block (~250 fat blocks, 512 thr)

typedef unsigned short bf16t;
typedef __attribute__((ext_vector_type(8))) short short8;
typedef __attribute__((ext_vector_type(4))) float f32x4;

static __device__ __forceinline__ float2 up2(unsigned u) {
    return make_float2(__uint_as_float(u << 16), __uint_as_float(u & 0xffff0000u));
}
static __device__ __forceinline__ bf16t f2bf(float f) {
    unsigned u = __float_as_uint(f);
    u += 0x7fffu + ((u >> 16) & 1u);  // round-to-nearest-even (finite values)
    return (bf16t)(u >> 16);
}
static __device__ __forceinline__ unsigned pk2(float a, float b) {
    return (unsigned)f2bf(a) | ((unsigned)f2bf(b) << 16);
}

// ---------------- pass 1: LDS counting-sort of edges into receiver/sender buckets ----------------
// R entry = (r&255)<<24 | s ; S entry = s&255 (u8). Last 2 blocks do W2-fragment prep.
// FAT blocks: 512 threads x 6400 edges (~250 blocks, 1/CU) — k_bucket is per-block-fixed-
// overhead bound (round 7: more blocks = slower). R+S scans fused into ONE packed scan.
__global__ void k_bucket(const int* __restrict__ S, const int* __restrict__ R,
                         unsigned* __restrict__ bufR, unsigned char* __restrict__ bufS,
                         int* __restrict__ gCntR, int* __restrict__ gCntS,
                         const float* __restrict__ W2, bf16t* __restrict__ W2f,
                         int nE, int nB) {
    __shared__ int histR[NBMAX], lstR[NBMAX], baseR[NBMAX];
    __shared__ int histS[NBMAX], lstS[NBMAX], baseS[NBMAX];
    __shared__ int sm[NBMAX];
    __shared__ unsigned sortedR[BKCHUNK];
    __shared__ unsigned short bOfR[BKCHUNK];
    __shared__ unsigned char sortedS[BKCHUNK];
    __shared__ unsigned short bOfS[BKCHUNK];
    int t = threadIdx.x;
    int nSort = gridDim.x - 2;
    if (blockIdx.x >= nSort) {
        // W2 -> MFMA B^T fragment prep: n = nt*16+(lane&15), k = kh*32+(lane>>4)*8+j
        int tt = (blockIdx.x - nSort) * blockDim.x + t;
        if (tt < 1024) {
            int nt = tt >> 7, kh = (tt >> 6) & 1, lane = tt & 63;
            int n = nt * 16 + (lane & 15);
            int k0 = kh * 32 + (lane >> 4) * 8;
            uint4 p;
            p.x = pk2(W2[(k0 + 0) * 128 + n], W2[(k0 + 1) * 128 + n]);
            p.y = pk2(W2[(k0 + 2) * 128 + n], W2[(k0 + 3) * 128 + n]);
            p.z = pk2(W2[(k0 + 4) * 128 + n], W2[(k0 + 5) * 128 + n]);
            p.w = pk2(W2[(k0 + 6) * 128 + n], W2[(k0 + 7) * 128 + n]);
            ((uint4*)W2f)[tt] = p;
        }
        return;
    }
    histR[t] = 0; histS[t] = 0;   // t in [0,512) == NBMAX
    __syncthreads();
    int chunk = (nE + nSort - 1) / nSort;
    int e0 = blockIdx.x * chunk;
    int e1 = min(e0 + chunk, nE);
    for (int e = e0 + t; e < e1; e += 512) {
        atomicAdd(&histR[R[e] >> 8], 1);
        atomicAdd(&histS[S[e] >> 8], 1);
    }
    __syncthreads();
    // fused packed exclusive scan over the 512 bins (R in low16, S in high16)
    int cR = histR[t], cS = histS[t];
    int pv = cR | (cS << 16);
    sm[t] = pv;
    __syncthreads();
    for (int off = 1; off < 512; off <<= 1) {
        int y = (t >= off) ? sm[t - off] : 0;
        __syncthreads();
        sm[t] += y;
        __syncthreads();
    }
    int ex = sm[t] - pv;
    lstR[t] = ex & 0xFFFF;
    lstS[t] = (ex >> 16) & 0xFFFF;
    if (t < nB) {
        baseR[t] = cR ? atomicAdd(&gCntR[t], cR) : 0;
        baseS[t] = cS ? atomicAdd(&gCntS[t], cS) : 0;
    }
    histR[t] = 0; histS[t] = 0;   // reuse as cursors
    __syncthreads();
    for (int e = e0 + t; e < e1; e += 512) {
        int r = R[e], s = S[e];
        int br = r >> 8;
        int p = lstR[br] + atomicAdd(&histR[br], 1);
        sortedR[p] = ((unsigned)(r & 255) << 24) | (unsigned)s;
        bOfR[p] = (unsigned short)br;
        int bs = s >> 8;
        int p2 = lstS[bs] + atomicAdd(&histS[bs], 1);
        sortedS[p2] = (unsigned char)(s & 255);
        bOfS[p2] = (unsigned short)bs;
    }
    __syncthreads();
    int cnt = e1 - e0;
    for (int i = t; i < cnt; i += 512) {
        int b = bOfR[i];
        int slot = baseR[b] + (i - lstR[b]);
        if (slot < BCAP) bufR[(size_t)b * BCAP + slot] = sortedR[i];
        int b2 = bOfS[i];
        int slot2 = baseS[b2] + (i - lstS[b2]);
        if (slot2 < BCAP) bufS[(size_t)b2 * BCAP + slot2] = sortedS[i];
    }
}

// ---------------- pass 2: per-bucket CSR + degR/inv_r + inv_s + xs prep (256 nodes/bucket) ----------------
__global__ void k_pass2(const unsigned* __restrict__ bufR, const unsigned char* __restrict__ bufS,
                        const int* __restrict__ gCntR, const int* __restrict__ gCntS,
                        const float* __restrict__ x,
                        int* __restrict__ csr, int* __restrict__ cur, int* __restrict__ degR,
                        float* __restrict__ inv_r, float* __restrict__ inv_s,
                        bf16t* __restrict__ xs, int nN, int nB) {
    __shared__ int hist[256], incl[256], curs[256], histS[256];
    __shared__ int sm[256];
    __shared__ int gex[NBMAX];
    int t = threadIdx.x;
    int b = blockIdx.x;
    // inline exclusive scan of gCntR -> global edge base per bucket
    {
        int c0 = (2 * t < nB) ? gCntR[2 * t] : 0;
        int c1 = (2 * t + 1 < nB) ? gCntR[2 * t + 1] : 0;
        int ps = c0 + c1;
        sm[t] = ps;
        __syncthreads();
        for (int off = 1; off < 256; off <<= 1) {
            int y = (t >= off) ? sm[t - off] : 0;
            __syncthreads();
            sm[t] += y;
            __syncthreads();
        }
        int ex = sm[t] - ps;
        gex[2 * t] = ex;
        gex[2 * t + 1] = ex + c0;
    }
    hist[t] = 0; curs[t] = 0; histS[t] = 0;
    __syncthreads();
    int gb = gex[b];
    int cnt = gCntR[b];
    const unsigned* buf = bufR + (size_t)b * BCAP;
    for (int i = t; i < cnt; i += 256) atomicAdd(&hist[buf[i] >> 24], 1);
    __syncthreads();
    int v = hist[t];
    sm[t] = v;
    __syncthreads();
    for (int off = 1; off < 256; off <<= 1) {
        int y = (t >= off) ? sm[t - off] : 0;
        __syncthreads();
        sm[t] += y;
        __syncthreads();
    }
    incl[t] = sm[t];  // inclusive scan of bin counts
    __syncthreads();
    int n0 = b << 8;
    int n = n0 + t;
    if (n < nN) {
        degR[n] = v;
        cur[n] = gb + incl[t];  // end offset (consumers use cur-deg)
        inv_r[n] = rsqrtf(fmaxf((float)v, 1.f));
    }
    for (int i = t; i < cnt; i += 256) {
        unsigned p = buf[i];
        int rl = p >> 24;
        int s = p & 0xFFFFFF;
        int pos = gb + (incl[rl] - hist[rl]) + atomicAdd(&curs[rl], 1);
        csr[pos] = s;  // contiguous ~16KB window per block
    }
    // ---- sender part: out-degree -> inv_s + xs prep (bf16) ----
    int cntS = gCntS[b];
    const unsigned char* bufs = bufS + (size_t)b * BCAP;
    for (int i = t; i < cntS; i += 256) atomicAdd(&histS[bufs[i]], 1);
    __syncthreads();
    if (n < nN) {
        float is = rsqrtf(fmaxf((float)histS[t], 1.f));
        inv_s[n] = is;
        float w[9];
#pragma unroll
        for (int k = 0; k < 9; k++) w[k] = x[(size_t)n * 9 + k] * is;
        uint4 pa, pb;
        pa.x = pk2(w[0], w[1]); pa.y = pk2(w[2], w[3]);
        pa.z = pk2(w[4], w[5]); pa.w = pk2(w[6], w[7]);
        pb.x = pk2(w[8], is);   pb.y = 0; pb.z = 0; pb.w = 0;
        uint4* o = (uint4*)(xs + (size_t)n * 16);
        o[0] = pa;
        o[1] = pb;
    }
}

// ---------------- fused layer-1 agg + dense: quarter-wave per node, 16 edges in flight ----------------
__global__ void k_h1f(const unsigned* __restrict__ xs32, const float* __restrict__ W1,
                      const float* __restrict__ b1,
                      const int* __restrict__ csr, const int* __restrict__ cur,
                      const int* __restrict__ degR, const float* __restrict__ inv_r,
                      const float* __restrict__ inv_s,
                      bf16t* __restrict__ h1s, float* __restrict__ warr, int nN) {
    __shared__ float Wl[9 * 64];
    __shared__ float bl[64];
    for (int i = threadIdx.x; i < 9 * 64; i += blockDim.x) Wl[i] = W1[i];
    if (threadIdx.x < 64) bl[threadIdx.x] = b1[threadIdx.x];
    __syncthreads();
    int lane = threadIdx.x & 63;
    int wave = threadIdx.x >> 6;
    int n = blockIdx.x * 16 + wave * 4 + (lane >> 4);
    int ql = lane & 15;
    int g = ql >> 2;      // edge slot within quarter (4 edges in parallel)
    int f2 = ql & 3;      // uint2 index into the 32B xs row
    int nc = min(n, nN - 1);
    int deg = degR[nc];
    int st = cur[nc] - deg;
    float4 A0 = {0.f, 0.f, 0.f, 0.f}, A1 = A0, A2 = A0, A3 = A0;
    int i = 0;
    for (; i + 16 <= deg; i += 16) {
        int ea = csr[st + i + g];
        int eb = csr[st + i + 4 + g];
        int ec = csr[st + i + 8 + g];
        int ed = csr[st + i + 12 + g];
        uint2 u0 = *(const uint2*)(xs32 + (size_t)ea * 8 + f2 * 2);
        uint2 u1 = *(const uint2*)(xs32 + (size_t)eb * 8 + f2 * 2);
        uint2 u2 = *(const uint2*)(xs32 + (size_t)ec * 8 + f2 * 2);
        uint2 u3 = *(const uint2*)(xs32 + (size_t)ed * 8 + f2 * 2);
        float2 a = up2(u0.x), b = up2(u0.y);
        A0.x += a.x; A0.y += a.y; A0.z += b.x; A0.w += b.y;
        a = up2(u1.x); b = up2(u1.y);
        A1.x += a.x; A1.y += a.y; A1.z += b.x; A1.w += b.y;
        a = up2(u2.x); b = up2(u2.y);
        A2.x += a.x; A2.y += a.y; A2.z += b.x; A2.w += b.y;
        a = up2(u3.x); b = up2(u3.y);
        A3.x += a.x; A3.y += a.y; A3.z += b.x; A3.w += b.y;
    }
    for (; i + 4 <= deg; i += 4) {
        int ea = csr[st + i + g];
        uint2 u0 = *(const uint2*)(xs32 + (size_t)ea * 8 + f2 * 2);
        float2 a = up2(u0.x), b = up2(u0.y);
        A0.x += a.x; A0.y += a.y; A0.z += b.x; A0.w += b.y;
    }
    if (g < deg - i) {
        int ea = csr[st + i + g];
        uint2 u0 = *(const uint2*)(xs32 + (size_t)ea * 8 + f2 * 2);
        float2 a = up2(u0.x), b = up2(u0.y);
        A1.x += a.x; A1.y += a.y; A1.z += b.x; A1.w += b.y;
    }
    float4 vq = {(A0.x + A1.x) + (A2.x + A3.x), (A0.y + A1.y) + (A2.y + A3.y),
                 (A0.z + A1.z) + (A2.z + A3.z), (A0.w + A1.w) + (A2.w + A3.w)};
    vq.x += __shfl_xor(vq.x, 4); vq.y += __shfl_xor(vq.y, 4);
    vq.z += __shfl_xor(vq.z, 4); vq.w += __shfl_xor(vq.w, 4);
    vq.x += __shfl_xor(vq.x, 8); vq.y += __shfl_xor(vq.y, 8);
    vq.z += __shfl_xor(vq.z, 8); vq.w += __shfl_xor(vq.w, 8);
    int base = lane & 48;
    float xv[9];
    xv[0] = __shfl(vq.x, base + 0); xv[1] = __shfl(vq.y, base + 0);
    xv[2] = __shfl(vq.z, base + 0); xv[3] = __shfl(vq.w, base + 0);
    xv[4] = __shfl(vq.x, base + 1); xv[5] = __shfl(vq.y, base + 1);
    xv[6] = __shfl(vq.z, base + 1); xv[7] = __shfl(vq.w, base + 1);
    xv[8] = __shfl(vq.x, base + 2);
    float w = __shfl(vq.y, base + 2);
    float ir = inv_r[nc];
    float is = inv_s[nc];
    int c0 = ql * 4;
    float acc[4];
#pragma unroll
    for (int j = 0; j < 4; j++) acc[j] = w * bl[c0 + j];
#pragma unroll
    for (int k = 0; k < 9; k++) {
        float4 wv = *(const float4*)(Wl + k * 64 + c0);
        acc[0] += xv[k] * wv.x;
        acc[1] += xv[k] * wv.y;
        acc[2] += xv[k] * wv.z;
        acc[3] += xv[k] * wv.w;
    }
    if (n < nN) {
        float v0 = fmaxf(acc[0] * ir, 0.f) * is;
        float v1 = fmaxf(acc[1] * ir, 0.f) * is;
        float v2 = fmaxf(acc[2] * ir, 0.f) * is;
        float v3 = fmaxf(acc[3] * ir, 0.f) * is;
        uint2 pv;
        pv.x = pk2(v0, v1);
        pv.y = pk2(v2, v3);
        *(uint2*)(h1s + (size_t)n * 64 + c0) = pv;
        if (ql == 0) warr[n] = w;
    }
}

// ---------------- fused layer-2 gather + MFMA 64->128->2 (temporal half-row split) ----------------
// block = 32 nodes (2 waves x 16), 128 threads; grid = nN/32. Phase 1: each wave owns 16
// nodes (4 lanes/node, uint4 16B/lane) and gathers in TWO sequential passes: pass A reads
// bytes [0,64) of each edge's h1 row, pass B reads [64,128). Device-wide hot set halves
// (12.8 -> 6.4MB) -> L2 hit ~31% -> ~60%, cutting L3 random traffic ~2x. Per-wave MLP
// doubles (16 chains x 4 in flight) so aggregate loads-in-flight/CU is unchanged vs the
// 16-node-block scheme. Phase 2: each wave runs the MFMA for its OWN 16 zl rows (no
// duplication) and writes t — round-2-verified epilogue structure.
__global__ void __launch_bounds__(128, 8)
k_l2f(const unsigned* __restrict__ h32, const bf16t* __restrict__ W2f,
      const float* __restrict__ b2, const float* __restrict__ W3,
      const float* __restrict__ inv_r, const float* __restrict__ inv_s,
      const float* __restrict__ warr,
      const int* __restrict__ csr, const int* __restrict__ cur,
      const int* __restrict__ degR,
      float* __restrict__ t, float* __restrict__ dout, int outSize, int nN) {
    __shared__ float b2l[128];
    __shared__ float W3l[256];
    __shared__ unsigned zl[32 * 36];  // 32 rows x 144B
    for (int i = threadIdx.x; i < 128; i += blockDim.x) b2l[i] = b2[i];
    for (int i = threadIdx.x; i < 256; i += blockDim.x) W3l[i] = W3[i];
    if (blockIdx.x == 0)
        for (int i = threadIdx.x; i < outSize; i += blockDim.x) dout[i] = 0.f;  // before k_poolg
    int lane = threadIdx.x & 63;
    int wave = threadIdx.x >> 6;    // 0..1
    int g4 = lane >> 2;             // group index 0..15 (one node per 4-lane group)
    int sub = lane & 3;             // uint4 index within the 64B half-row
    int n0w = blockIdx.x * 32 + wave * 16;
    int roff = wave * 16 + g4;
    int nc = min(n0w + g4, nN - 1);
    int deg = degR[nc];
    int st = cur[nc] - deg;
    // ---- phase 1: two temporal passes over the edges (half-row each), 4 edges in flight ----
#pragma unroll
    for (int h = 0; h < 2; h++) {
        const unsigned* hb = h32 + h * 16 + sub * 4;
        float a0 = 0.f, a1 = 0.f, a2 = 0.f, a3 = 0.f;
        float a4 = 0.f, a5 = 0.f, a6 = 0.f, a7 = 0.f;
        int i = 0;
        for (; i + 4 <= deg; i += 4) {
            int e0 = csr[st + i + 0];
            int e1 = csr[st + i + 1];
            int e2 = csr[st + i + 2];
            int e3 = csr[st + i + 3];
            uint4 u0 = *(const uint4*)(hb + (size_t)e0 * 32);
            uint4 u1 = *(const uint4*)(hb + (size_t)e1 * 32);
            uint4 u2 = *(const uint4*)(hb + (size_t)e2 * 32);
            uint4 u3 = *(const uint4*)(hb + (size_t)e3 * 32);
            float2 p;
            p = up2(u0.x); a0 += p.x; a1 += p.y;
            p = up2(u0.y); a2 += p.x; a3 += p.y;
            p = up2(u0.z); a4 += p.x; a5 += p.y;
            p = up2(u0.w); a6 += p.x; a7 += p.y;
            p = up2(u1.x); a0 += p.x; a1 += p.y;
            p = up2(u1.y); a2 += p.x; a3 += p.y;
            p = up2(u1.z); a4 += p.x; a5 += p.y;
            p = up2(u1.w); a6 += p.x; a7 += p.y;
            p = up2(u2.x); a0 += p.x; a1 += p.y;
            p = up2(u2.y); a2 += p.x; a3 += p.y;
            p = up2(u2.z); a4 += p.x; a5 += p.y;
            p = up2(u2.w); a6 += p.x; a7 += p.y;
            p = up2(u3.x); a0 += p.x; a1 += p.y;
            p = up2(u3.y); a2 += p.x; a3 += p.y;
            p = up2(u3.z); a4 += p.x; a5 += p.y;
            p = up2(u3.w); a6 += p.x; a7 += p.y;
        }
        for (; i < deg; i++) {
            int e0 = csr[st + i];
            uint4 u0 = *(const uint4*)(hb + (size_t)e0 * 32);
            float2 p;
            p = up2(u0.x); a0 += p.x; a1 += p.y;
            p = up2(u0.y); a2 += p.x; a3 += p.y;
            p = up2(u0.z); a4 += p.x; a5 += p.y;
            p = up2(u0.w); a6 += p.x; a7 += p.y;
        }
        uint4 pv;
        pv.x = pk2(a0, a1);
        pv.y = pk2(a2, a3);
        pv.z = pk2(a4, a5);
        pv.w = pk2(a6, a7);
        *(uint4*)(zl + roff * 36 + h * 16 + sub * 4) = pv;
    }
    __syncthreads();  // b2l/W3l (zl rows are wave-private)
    int m = lane & 15;
    int q = lane >> 4;
    int row = wave * 16 + m;
    short8 afr0 = *(const short8*)(zl + row * 36 + q * 4);
    short8 afr1 = *(const short8*)(zl + row * 36 + 16 + q * 4);
    float w4[4], ir4[4], is4[4];
#pragma unroll
    for (int reg = 0; reg < 4; reg++) {
        int nr = min(n0w + q * 4 + reg, nN - 1);
        w4[reg] = warr[nr];
        ir4[reg] = inv_r[nr];
        is4[reg] = inv_s[nr];
    }
    float p0[4] = {0.f, 0.f, 0.f, 0.f}, p1[4] = {0.f, 0.f, 0.f, 0.f};
#pragma unroll
    for (int nt = 0; nt < 8; nt++) {
        short8 b0 = *(const short8*)(W2f + ((size_t)(nt * 2 + 0) * 64 + lane) * 8);
        short8 b1 = *(const short8*)(W2f + ((size_t)(nt * 2 + 1) * 64 + lane) * 8);
        f32x4 acc = {0.f, 0.f, 0.f, 0.f};
        acc = __builtin_amdgcn_mfma_f32_16x16x32_bf16(afr0, b0, acc, 0, 0, 0);
        acc = __builtin_amdgcn_mfma_f32_16x16x32_bf16(afr1, b1, acc, 0, 0, 0);
        int col = nt * 16 + m;
        float bc = b2l[col];
        float w30 = W3l[col * 2 + 0];
        float w31 = W3l[col * 2 + 1];
#pragma unroll
        for (int reg = 0; reg < 4; reg++) {
            float h = fmaxf((acc[reg] + w4[reg] * bc) * ir4[reg], 0.f) * is4[reg];
            p0[reg] += h * w30;
            p1[reg] += h * w31;
        }
    }
#pragma unroll
    for (int mask = 1; mask < 16; mask <<= 1) {
#pragma unroll
        for (int reg = 0; reg < 4; reg++) {
            p0[reg] += __shfl_xor(p0[reg], mask);
            p1[reg] += __shfl_xor(p1[reg], mask);
        }
    }
    if (m == 0) {
#pragma unroll
        for (int reg = 0; reg < 4; reg++) {
            int nr = n0w + q * 4 + reg;
            if (nr < nN) *(float2*)(t + (size_t)nr * 2) = make_float2(p0[reg], p1[reg]);
        }
    }
}

// ---------------- pooling: 8 lanes per node over CSR (~49 waves/CU supplied) ----------------
__global__ void k_poolg(const float* __restrict__ t, const float* __restrict__ inv_r,
                        const float* __restrict__ warr, const float* __restrict__ b3,
                        const int* __restrict__ csr, const int* __restrict__ cur,
                        const int* __restrict__ degR, const int* __restrict__ batch,
                        float* out, int nN, int outSize) {
    __shared__ float sm[256];
    for (int i = threadIdx.x; i < 256; i += blockDim.x) sm[i] = 0.f;
    __syncthreads();
    int tid = blockIdx.x * blockDim.x + threadIdx.x;
    int n = tid >> 3;
    int sub = tid & 7;
    if (n < nN) {
        int deg = degR[n];
        int st = cur[n] - deg;
        float a0 = 0.f, a1 = 0.f, c0 = 0.f, c1 = 0.f;
        int i = sub;
        for (; i + 8 < deg; i += 16) {
            int sa = csr[st + i], sb = csr[st + i + 8];
            float2 va = ((const float2*)t)[sa];
            float2 vb = ((const float2*)t)[sb];
            a0 += va.x; a1 += va.y;
            c0 += vb.x; c1 += vb.y;
        }
        for (; i < deg; i += 8) {
            float2 va = ((const float2*)t)[csr[st + i]];
            a0 += va.x; a1 += va.y;
        }
        float p0 = a0 + c0;
        float p1 = a1 + c1;
        // reduce across the 8-lane group
        p0 += __shfl_xor(p0, 1); p1 += __shfl_xor(p1, 1);
        p0 += __shfl_xor(p0, 2); p1 += __shfl_xor(p1, 2);
        p0 += __shfl_xor(p0, 4); p1 += __shfl_xor(p1, 4);
        if (sub == 0) {
            float ir = inv_r[n];
            float wb = warr[n] * ir;
            int g = batch[n];
            atomicAdd(&sm[2 * g + 0], p0 * ir + wb * b3[0]);
            atomicAdd(&sm[2 * g + 1], p1 * ir + wb * b3[1]);
        }
    }
    __syncthreads();
    // skip the zero bins (a block touches only a few graphs)
    for (int i = threadIdx.x; i < outSize; i += blockDim.x) {
        float v = sm[i];
        if (v != 0.f) atomicAdd(&out[i], v);
    }
}

extern "C" void kernel_launch(void* const* d_in, const int* in_sizes, int n_in,
                              void* d_out, int out_size, void* d_ws, size_t ws_size,
                              hipStream_t stream) {
    const float* x     = (const float*)d_in[0];
    const int*   S     = (const int*)d_in[1];
    const int*   R     = (const int*)d_in[2];
    const int*   batch = (const int*)d_in[3];
    const float* W1 = (const float*)d_in[5];
    const float* b1 = (const float*)d_in[6];
    const float* W2 = (const float*)d_in[7];
    const float* b2 = (const float*)d_in[8];
    const float* W3 = (const float*)d_in[9];
    const float* b3 = (const float*)d_in[10];

    int nN = in_sizes[0] / 9;
    int nE = in_sizes[1];
    int nB = (nN + 255) / 256;  // 256-node buckets; requires nB <= NBMAX

    char* ws = (char*)d_ws;
    int*   cur   = (int*)ws;                          // nN
    int*   degR  = cur + nN;                          // nN
    float* inv_s = (float*)(degR + nN);               // nN
    float* inv_r = inv_s + nN;                        // nN
    float* warr  = inv_r + nN;                        // nN
    int*   gCntR = (int*)(warr + nN);                 // NBMAX
    int*   gCntS = gCntR + NBMAX;                     // NBMAX
    int*   csr   = gCntS + NBMAX;                     // nE
    bf16t* xs    = (bf16t*)(csr + nE);                // nN*16 bf16 (3.2 MB)
    bf16t* W2f   = xs + (size_t)nN * 16;              // 8192 bf16 (16 KB)
    char*  regA  = (char*)(W2f + 8192);
    // aliasing (bufR/bufS dead after k_pass2; h1s written by k_h1f afterwards)
    unsigned*      bufR = (unsigned*)regA;                                // NBMAX*BCAP*4 = 10.5 MB
    unsigned char* bufS = (unsigned char*)(bufR + (size_t)NBMAX * BCAP);  // NBMAX*BCAP   = 2.6 MB
    bf16t* h1s = (bf16t*)regA;                        // nN*64 bf16 (12.8 MB)
    float* t   = (float*)(regA + (size_t)NBMAX * BCAP * 5);  // nN*2 fp32 (past both regions)

    const int B = 256;

    // ---- build: fat bucket sort (~250 sort blocks x 512 thr + 2 W2-prep), per-bucket CSR etc. ----
    int nSort = (nE + BKCHUNK - 1) / BKCHUNK;
    if (nSort < 1) nSort = 1;
    hipMemsetAsync(gCntR, 0, 2 * NBMAX * 4, stream);
    k_bucket<<<nSort + 2, 512, 0, stream>>>(S, R, bufR, bufS, gCntR, gCntS, W2, W2f, nE, nB);
    k_pass2<<<nB, B, 0, stream>>>(bufR, bufS, gCntR, gCntS, x, csr, cur, degR,
                                  inv_r, inv_s, xs, nN, nB);

    // ---- layer 1: fused gather + 9->64 dense ----
    k_h1f<<<(nN + 15) / 16, B, 0, stream>>>((const unsigned*)xs, W1, b1, csr, cur, degR,
                                            inv_r, inv_s, h1s, warr, nN);

    // ---- layers 2+3: fused gather (half-row temporal split) + MFMA 64->128->2 ----
    k_l2f<<<(nN + 31) / 32, 128, 0, stream>>>((const unsigned*)h1s, W2f, b2, W3,
                                              inv_r, inv_s, warr, csr, cur, degR,
                                              t, (float*)d_out, out_size, nN);

    // ---- fused layer-3 aggregation + bias + pooling (8 lanes/node) ----
    k_poolg<<<(nN * 8 + B - 1) / B, B, 0, stream>>>(t, inv_r, warr, b3, csr, cur, degR, batch,
                                                    (float*)d_out, nN, out_size);
}

// Round 10
// 203.813 us; speedup vs baseline: 1.1066x; 1.1066x over previous
//
#include <hip/hip_runtime.h>
#include <hip/hip_bf16.h>
#include <cstddef>

#define NBMAX 512     // max buckets (256 nodes each -> supports nN <= 131072)
#define BCAP 5120     // per-bucket edge capacity; mean ~4092, sigma ~64
#define BKCHUNK 6400  // max edges per bucket-sort block (~250 fat blocks, 512 thr)

typedef unsigned short bf16t;
typedef __attribute__((ext_vector_type(8))) short short8;
typedef __attribute__((ext_vector_type(4))) float f32x4;

static __device__ __forceinline__ float2 up2(unsigned u) {
    return make_float2(__uint_as_float(u << 16), __uint_as_float(u & 0xffff0000u));
}
static __device__ __forceinline__ bf16t f2bf(float f) {
    unsigned u = __float_as_uint(f);
    u += 0x7fffu + ((u >> 16) & 1u);  // round-to-nearest-even (finite values)
    return (bf16t)(u >> 16);
}
static __device__ __forceinline__ unsigned pk2(float a, float b) {
    return (unsigned)f2bf(a) | ((unsigned)f2bf(b) << 16);
}

// ---------------- pass 1: LDS counting-sort of edges into receiver/sender buckets ----------------
// R entry = (r&255)<<24 | s ; S entry = s&255 (u8). Last 2 blocks do W2-fragment prep.
// FAT blocks: 512 threads x 6400 edges (~250 blocks, 1/CU) — k_bucket is per-block-fixed-
// overhead bound (round 7: more blocks = slower). R+S scans fused into ONE packed scan.
__global__ void k_bucket(const int* __restrict__ S, const int* __restrict__ R,
                         unsigned* __restrict__ bufR, unsigned char* __restrict__ bufS,
                         int* __restrict__ gCntR, int* __restrict__ gCntS,
                         const float* __restrict__ W2, bf16t* __restrict__ W2f,
                         int nE, int nB) {
    __shared__ int histR[NBMAX], lstR[NBMAX], baseR[NBMAX];
    __shared__ int histS[NBMAX], lstS[NBMAX], baseS[NBMAX];
    __shared__ int sm[NBMAX];
    __shared__ unsigned sortedR[BKCHUNK];
    __shared__ unsigned short bOfR[BKCHUNK];
    __shared__ unsigned char sortedS[BKCHUNK];
    __shared__ unsigned short bOfS[BKCHUNK];
    int t = threadIdx.x;
    int nSort = gridDim.x - 2;
    if (blockIdx.x >= nSort) {
        // W2 -> MFMA B^T fragment prep: n = nt*16+(lane&15), k = kh*32+(lane>>4)*8+j
        int tt = (blockIdx.x - nSort) * blockDim.x + t;
        if (tt < 1024) {
            int nt = tt >> 7, kh = (tt >> 6) & 1, lane = tt & 63;
            int n = nt * 16 + (lane & 15);
            int k0 = kh * 32 + (lane >> 4) * 8;
            uint4 p;
            p.x = pk2(W2[(k0 + 0) * 128 + n], W2[(k0 + 1) * 128 + n]);
            p.y = pk2(W2[(k0 + 2) * 128 + n], W2[(k0 + 3) * 128 + n]);
            p.z = pk2(W2[(k0 + 4) * 128 + n], W2[(k0 + 5) * 128 + n]);
            p.w = pk2(W2[(k0 + 6) * 128 + n], W2[(k0 + 7) * 128 + n]);
            ((uint4*)W2f)[tt] = p;
        }
        return;
    }
    histR[t] = 0; histS[t] = 0;   // t in [0,512) == NBMAX
    __syncthreads();
    int chunk = (nE + nSort - 1) / nSort;
    int e0 = blockIdx.x * chunk;
    int e1 = min(e0 + chunk, nE);
    for (int e = e0 + t; e < e1; e += 512) {
        atomicAdd(&histR[R[e] >> 8], 1);
        atomicAdd(&histS[S[e] >> 8], 1);
    }
    __syncthreads();
    // fused packed exclusive scan over the 512 bins (R in low16, S in high16)
    int cR = histR[t], cS = histS[t];
    int pv = cR | (cS << 16);
    sm[t] = pv;
    __syncthreads();
    for (int off = 1; off < 512; off <<= 1) {
        int y = (t >= off) ? sm[t - off] : 0;
        __syncthreads();
        sm[t] += y;
        __syncthreads();
    }
    int ex = sm[t] - pv;
    lstR[t] = ex & 0xFFFF;
    lstS[t] = (ex >> 16) & 0xFFFF;
    if (t < nB) {
        baseR[t] = cR ? atomicAdd(&gCntR[t], cR) : 0;
        baseS[t] = cS ? atomicAdd(&gCntS[t], cS) : 0;
    }
    histR[t] = 0; histS[t] = 0;   // reuse as cursors
    __syncthreads();
    for (int e = e0 + t; e < e1; e += 512) {
        int r = R[e], s = S[e];
        int br = r >> 8;
        int p = lstR[br] + atomicAdd(&histR[br], 1);
        sortedR[p] = ((unsigned)(r & 255) << 24) | (unsigned)s;
        bOfR[p] = (unsigned short)br;
        int bs = s >> 8;
        int p2 = lstS[bs] + atomicAdd(&histS[bs], 1);
        sortedS[p2] = (unsigned char)(s & 255);
        bOfS[p2] = (unsigned short)bs;
    }
    __syncthreads();
    int cnt = e1 - e0;
    for (int i = t; i < cnt; i += 512) {
        int b = bOfR[i];
        int slot = baseR[b] + (i - lstR[b]);
        if (slot < BCAP) bufR[(size_t)b * BCAP + slot] = sortedR[i];
        int b2 = bOfS[i];
        int slot2 = baseS[b2] + (i - lstS[b2]);
        if (slot2 < BCAP) bufS[(size_t)b2 * BCAP + slot2] = sortedS[i];
    }
}

// ---------------- pass 2: per-bucket CSR + degR/inv_r + inv_s + xs prep (256 nodes/bucket) ----------------
__global__ void k_pass2(const unsigned* __restrict__ bufR, const unsigned char* __restrict__ bufS,
                        const int* __restrict__ gCntR, const int* __restrict__ gCntS,
                        const float* __restrict__ x,
                        int* __restrict__ csr, int* __restrict__ cur, int* __restrict__ degR,
                        float* __restrict__ inv_r, float* __restrict__ inv_s,
                        bf16t* __restrict__ xs, int nN, int nB) {
    __shared__ int hist[256], incl[256], curs[256], histS[256];
    __shared__ int sm[256];
    __shared__ int gex[NBMAX];
    int t = threadIdx.x;
    int b = blockIdx.x;
    // inline exclusive scan of gCntR -> global edge base per bucket
    {
        int c0 = (2 * t < nB) ? gCntR[2 * t] : 0;
        int c1 = (2 * t + 1 < nB) ? gCntR[2 * t + 1] : 0;
        int ps = c0 + c1;
        sm[t] = ps;
        __syncthreads();
        for (int off = 1; off < 256; off <<= 1) {
            int y = (t >= off) ? sm[t - off] : 0;
            __syncthreads();
            sm[t] += y;
            __syncthreads();
        }
        int ex = sm[t] - ps;
        gex[2 * t] = ex;
        gex[2 * t + 1] = ex + c0;
    }
    hist[t] = 0; curs[t] = 0; histS[t] = 0;
    __syncthreads();
    int gb = gex[b];
    int cnt = gCntR[b];
    const unsigned* buf = bufR + (size_t)b * BCAP;
    for (int i = t; i < cnt; i += 256) atomicAdd(&hist[buf[i] >> 24], 1);
    __syncthreads();
    int v = hist[t];
    sm[t] = v;
    __syncthreads();
    for (int off = 1; off < 256; off <<= 1) {
        int y = (t >= off) ? sm[t - off] : 0;
        __syncthreads();
        sm[t] += y;
        __syncthreads();
    }
    incl[t] = sm[t];  // inclusive scan of bin counts
    __syncthreads();
    int n0 = b << 8;
    int n = n0 + t;
    if (n < nN) {
        degR[n] = v;
        cur[n] = gb + incl[t];  // end offset (consumers use cur-deg)
        inv_r[n] = rsqrtf(fmaxf((float)v, 1.f));
    }
    for (int i = t; i < cnt; i += 256) {
        unsigned p = buf[i];
        int rl = p >> 24;
        int s = p & 0xFFFFFF;
        int pos = gb + (incl[rl] - hist[rl]) + atomicAdd(&curs[rl], 1);
        csr[pos] = s;  // contiguous ~16KB window per block
    }
    // ---- sender part: out-degree -> inv_s + xs prep (bf16) ----
    int cntS = gCntS[b];
    const unsigned char* bufs = bufS + (size_t)b * BCAP;
    for (int i = t; i < cntS; i += 256) atomicAdd(&histS[bufs[i]], 1);
    __syncthreads();
    if (n < nN) {
        float is = rsqrtf(fmaxf((float)histS[t], 1.f));
        inv_s[n] = is;
        float w[9];
#pragma unroll
        for (int k = 0; k < 9; k++) w[k] = x[(size_t)n * 9 + k] * is;
        uint4 pa, pb;
        pa.x = pk2(w[0], w[1]); pa.y = pk2(w[2], w[3]);
        pa.z = pk2(w[4], w[5]); pa.w = pk2(w[6], w[7]);
        pb.x = pk2(w[8], is);   pb.y = 0; pb.z = 0; pb.w = 0;
        uint4* o = (uint4*)(xs + (size_t)n * 16);
        o[0] = pa;
        o[1] = pb;
    }
}

// ---------------- fused layer-1 agg + dense: quarter-wave per node, 16 edges in flight ----------------
__global__ void k_h1f(const unsigned* __restrict__ xs32, const float* __restrict__ W1,
                      const float* __restrict__ b1,
                      const int* __restrict__ csr, const int* __restrict__ cur,
                      const int* __restrict__ degR, const float* __restrict__ inv_r,
                      const float* __restrict__ inv_s,
                      bf16t* __restrict__ h1s, float* __restrict__ warr, int nN) {
    __shared__ float Wl[9 * 64];
    __shared__ float bl[64];
    for (int i = threadIdx.x; i < 9 * 64; i += blockDim.x) Wl[i] = W1[i];
    if (threadIdx.x < 64) bl[threadIdx.x] = b1[threadIdx.x];
    __syncthreads();
    int lane = threadIdx.x & 63;
    int wave = threadIdx.x >> 6;
    int n = blockIdx.x * 16 + wave * 4 + (lane >> 4);
    int ql = lane & 15;
    int g = ql >> 2;      // edge slot within quarter (4 edges in parallel)
    int f2 = ql & 3;      // uint2 index into the 32B xs row
    int nc = min(n, nN - 1);
    int deg = degR[nc];
    int st = cur[nc] - deg;
    float4 A0 = {0.f, 0.f, 0.f, 0.f}, A1 = A0, A2 = A0, A3 = A0;
    int i = 0;
    for (; i + 16 <= deg; i += 16) {
        int ea = csr[st + i + g];
        int eb = csr[st + i + 4 + g];
        int ec = csr[st + i + 8 + g];
        int ed = csr[st + i + 12 + g];
        uint2 u0 = *(const uint2*)(xs32 + (size_t)ea * 8 + f2 * 2);
        uint2 u1 = *(const uint2*)(xs32 + (size_t)eb * 8 + f2 * 2);
        uint2 u2 = *(const uint2*)(xs32 + (size_t)ec * 8 + f2 * 2);
        uint2 u3 = *(const uint2*)(xs32 + (size_t)ed * 8 + f2 * 2);
        float2 a = up2(u0.x), b = up2(u0.y);
        A0.x += a.x; A0.y += a.y; A0.z += b.x; A0.w += b.y;
        a = up2(u1.x); b = up2(u1.y);
        A1.x += a.x; A1.y += a.y; A1.z += b.x; A1.w += b.y;
        a = up2(u2.x); b = up2(u2.y);
        A2.x += a.x; A2.y += a.y; A2.z += b.x; A2.w += b.y;
        a = up2(u3.x); b = up2(u3.y);
        A3.x += a.x; A3.y += a.y; A3.z += b.x; A3.w += b.y;
    }
    for (; i + 4 <= deg; i += 4) {
        int ea = csr[st + i + g];
        uint2 u0 = *(const uint2*)(xs32 + (size_t)ea * 8 + f2 * 2);
        float2 a = up2(u0.x), b = up2(u0.y);
        A0.x += a.x; A0.y += a.y; A0.z += b.x; A0.w += b.y;
    }
    if (g < deg - i) {
        int ea = csr[st + i + g];
        uint2 u0 = *(const uint2*)(xs32 + (size_t)ea * 8 + f2 * 2);
        float2 a = up2(u0.x), b = up2(u0.y);
        A1.x += a.x; A1.y += a.y; A1.z += b.x; A1.w += b.y;
    }
    float4 vq = {(A0.x + A1.x) + (A2.x + A3.x), (A0.y + A1.y) + (A2.y + A3.y),
                 (A0.z + A1.z) + (A2.z + A3.z), (A0.w + A1.w) + (A2.w + A3.w)};
    vq.x += __shfl_xor(vq.x, 4); vq.y += __shfl_xor(vq.y, 4);
    vq.z += __shfl_xor(vq.z, 4); vq.w += __shfl_xor(vq.w, 4);
    vq.x += __shfl_xor(vq.x, 8); vq.y += __shfl_xor(vq.y, 8);
    vq.z += __shfl_xor(vq.z, 8); vq.w += __shfl_xor(vq.w, 8);
    int base = lane & 48;
    float xv[9];
    xv[0] = __shfl(vq.x, base + 0); xv[1] = __shfl(vq.y, base + 0);
    xv[2] = __shfl(vq.z, base + 0); xv[3] = __shfl(vq.w, base + 0);
    xv[4] = __shfl(vq.x, base + 1); xv[5] = __shfl(vq.y, base + 1);
    xv[6] = __shfl(vq.z, base + 1); xv[7] = __shfl(vq.w, base + 1);
    xv[8] = __shfl(vq.x, base + 2);
    float w = __shfl(vq.y, base + 2);
    float ir = inv_r[nc];
    float is = inv_s[nc];
    int c0 = ql * 4;
    float acc[4];
#pragma unroll
    for (int j = 0; j < 4; j++) acc[j] = w * bl[c0 + j];
#pragma unroll
    for (int k = 0; k < 9; k++) {
        float4 wv = *(const float4*)(Wl + k * 64 + c0);
        acc[0] += xv[k] * wv.x;
        acc[1] += xv[k] * wv.y;
        acc[2] += xv[k] * wv.z;
        acc[3] += xv[k] * wv.w;
    }
    if (n < nN) {
        float v0 = fmaxf(acc[0] * ir, 0.f) * is;
        float v1 = fmaxf(acc[1] * ir, 0.f) * is;
        float v2 = fmaxf(acc[2] * ir, 0.f) * is;
        float v3 = fmaxf(acc[3] * ir, 0.f) * is;
        uint2 pv;
        pv.x = pk2(v0, v1);
        pv.y = pk2(v2, v3);
        *(uint2*)(h1s + (size_t)n * 64 + c0) = pv;
        if (ql == 0) warr[n] = w;
    }
}

// ---------------- fused layer-2 gather + MFMA 64->128->2 ----------------
// block = 16 nodes (2 waves), 128 threads; grid = nN/16.
// Phase 1: 8 lanes cover the 128B h1 row at 16B/lane (uint4), one node per 8-lane group,
// 4 edges in flight. Phase 2: both waves redundantly run the 16-row MFMA from shared zl;
// wave 0 writes t. (Half-row temporal split regressed: 128B line granularity doubles
// traffic — round 9. This full-row form is the measured floor: ~2.1 TB/s past-L2.)
__global__ void __launch_bounds__(128, 8)
k_l2f(const unsigned* __restrict__ h32, const bf16t* __restrict__ W2f,
      const float* __restrict__ b2, const float* __restrict__ W3,
      const float* __restrict__ inv_r, const float* __restrict__ inv_s,
      const float* __restrict__ warr,
      const int* __restrict__ csr, const int* __restrict__ cur,
      const int* __restrict__ degR,
      float* __restrict__ t, float* __restrict__ dout, int outSize, int nN) {
    __shared__ float b2l[128];
    __shared__ float W3l[256];
    __shared__ unsigned zl[16 * 36];  // 16 rows x 144B
    for (int i = threadIdx.x; i < 128; i += blockDim.x) b2l[i] = b2[i];
    for (int i = threadIdx.x; i < 256; i += blockDim.x) W3l[i] = W3[i];
    if (blockIdx.x == 0)
        for (int i = threadIdx.x; i < outSize; i += blockDim.x) dout[i] = 0.f;  // before k_poolg
    int lane = threadIdx.x & 63;
    int wave = threadIdx.x >> 6;    // 0..1
    int g3 = lane >> 3;             // group index 0..7 (one node per group)
    int sub = lane & 7;             // uint4 index into the 128B row
    int n0b = blockIdx.x * 16;
    // ---- phase 1: each 8-lane group aggregates its node, 4 edges in flight ----
    {
        int roff = wave * 8 + g3;
        int nc = min(n0b + roff, nN - 1);
        int deg = degR[nc];
        int st = cur[nc] - deg;
        float a0 = 0.f, a1 = 0.f, a2 = 0.f, a3 = 0.f;
        float a4 = 0.f, a5 = 0.f, a6 = 0.f, a7 = 0.f;
        int i = 0;
        for (; i + 4 <= deg; i += 4) {
            int e0 = csr[st + i + 0];
            int e1 = csr[st + i + 1];
            int e2 = csr[st + i + 2];
            int e3 = csr[st + i + 3];
            uint4 u0 = *(const uint4*)(h32 + (size_t)e0 * 32 + sub * 4);
            uint4 u1 = *(const uint4*)(h32 + (size_t)e1 * 32 + sub * 4);
            uint4 u2 = *(const uint4*)(h32 + (size_t)e2 * 32 + sub * 4);
            uint4 u3 = *(const uint4*)(h32 + (size_t)e3 * 32 + sub * 4);
            float2 p;
            p = up2(u0.x); a0 += p.x; a1 += p.y;
            p = up2(u0.y); a2 += p.x; a3 += p.y;
            p = up2(u0.z); a4 += p.x; a5 += p.y;
            p = up2(u0.w); a6 += p.x; a7 += p.y;
            p = up2(u1.x); a0 += p.x; a1 += p.y;
            p = up2(u1.y); a2 += p.x; a3 += p.y;
            p = up2(u1.z); a4 += p.x; a5 += p.y;
            p = up2(u1.w); a6 += p.x; a7 += p.y;
            p = up2(u2.x); a0 += p.x; a1 += p.y;
            p = up2(u2.y); a2 += p.x; a3 += p.y;
            p = up2(u2.z); a4 += p.x; a5 += p.y;
            p = up2(u2.w); a6 += p.x; a7 += p.y;
            p = up2(u3.x); a0 += p.x; a1 += p.y;
            p = up2(u3.y); a2 += p.x; a3 += p.y;
            p = up2(u3.z); a4 += p.x; a5 += p.y;
            p = up2(u3.w); a6 += p.x; a7 += p.y;
        }
        for (; i < deg; i++) {
            int e0 = csr[st + i];
            uint4 u0 = *(const uint4*)(h32 + (size_t)e0 * 32 + sub * 4);
            float2 p;
            p = up2(u0.x); a0 += p.x; a1 += p.y;
            p = up2(u0.y); a2 += p.x; a3 += p.y;
            p = up2(u0.z); a4 += p.x; a5 += p.y;
            p = up2(u0.w); a6 += p.x; a7 += p.y;
        }
        uint4 pv;
        pv.x = pk2(a0, a1);
        pv.y = pk2(a2, a3);
        pv.z = pk2(a4, a5);
        pv.w = pk2(a6, a7);
        *(uint4*)(zl + roff * 36 + sub * 4) = pv;
    }
    __syncthreads();  // zl rows cross waves (and b2l/W3l)
    int m = lane & 15;
    int q = lane >> 4;
    short8 afr0 = *(const short8*)(zl + m * 36 + q * 4);
    short8 afr1 = *(const short8*)(zl + m * 36 + 16 + q * 4);
    float w4[4], ir4[4], is4[4];
#pragma unroll
    for (int reg = 0; reg < 4; reg++) {
        int nr = min(n0b + q * 4 + reg, nN - 1);
        w4[reg] = warr[nr];
        ir4[reg] = inv_r[nr];
        is4[reg] = inv_s[nr];
    }
    float p0[4] = {0.f, 0.f, 0.f, 0.f}, p1[4] = {0.f, 0.f, 0.f, 0.f};
#pragma unroll
    for (int nt = 0; nt < 8; nt++) {
        short8 b0 = *(const short8*)(W2f + ((size_t)(nt * 2 + 0) * 64 + lane) * 8);
        short8 b1 = *(const short8*)(W2f + ((size_t)(nt * 2 + 1) * 64 + lane) * 8);
        f32x4 acc = {0.f, 0.f, 0.f, 0.f};
        acc = __builtin_amdgcn_mfma_f32_16x16x32_bf16(afr0, b0, acc, 0, 0, 0);
        acc = __builtin_amdgcn_mfma_f32_16x16x32_bf16(afr1, b1, acc, 0, 0, 0);
        int col = nt * 16 + m;
        float bc = b2l[col];
        float w30 = W3l[col * 2 + 0];
        float w31 = W3l[col * 2 + 1];
#pragma unroll
        for (int reg = 0; reg < 4; reg++) {
            float h = fmaxf((acc[reg] + w4[reg] * bc) * ir4[reg], 0.f) * is4[reg];
            p0[reg] += h * w30;
            p1[reg] += h * w31;
        }
    }
#pragma unroll
    for (int mask = 1; mask < 16; mask <<= 1) {
#pragma unroll
        for (int reg = 0; reg < 4; reg++) {
            p0[reg] += __shfl_xor(p0[reg], mask);
            p1[reg] += __shfl_xor(p1[reg], mask);
        }
    }
    if (wave == 0 && m == 0) {
#pragma unroll
        for (int reg = 0; reg < 4; reg++) {
            int nr = n0b + q * 4 + reg;
            if (nr < nN) *(float2*)(t + (size_t)nr * 2) = make_float2(p0[reg], p1[reg]);
        }
    }
}

// ---------------- pooling: 8 lanes per node over CSR (~49 waves/CU supplied) ----------------
__global__ void k_poolg(const float* __restrict__ t, const float* __restrict__ inv_r,
                        const float* __restrict__ warr, const float* __restrict__ b3,
                        const int* __restrict__ csr, const int* __restrict__ cur,
                        const int* __restrict__ degR, const int* __restrict__ batch,
                        float* out, int nN, int outSize) {
    __shared__ float sm[256];
    for (int i = threadIdx.x; i < 256; i += blockDim.x) sm[i] = 0.f;
    __syncthreads();
    int tid = blockIdx.x * blockDim.x + threadIdx.x;
    int n = tid >> 3;
    int sub = tid & 7;
    if (n < nN) {
        int deg = degR[n];
        int st = cur[n] - deg;
        float a0 = 0.f, a1 = 0.f, c0 = 0.f, c1 = 0.f;
        int i = sub;
        for (; i + 8 < deg; i += 16) {
            int sa = csr[st + i], sb = csr[st + i + 8];
            float2 va = ((const float2*)t)[sa];
            float2 vb = ((const float2*)t)[sb];
            a0 += va.x; a1 += va.y;
            c0 += vb.x; c1 += vb.y;
        }
        for (; i < deg; i += 8) {
            float2 va = ((const float2*)t)[csr[st + i]];
            a0 += va.x; a1 += va.y;
        }
        float p0 = a0 + c0;
        float p1 = a1 + c1;
        // reduce across the 8-lane group
        p0 += __shfl_xor(p0, 1); p1 += __shfl_xor(p1, 1);
        p0 += __shfl_xor(p0, 2); p1 += __shfl_xor(p1, 2);
        p0 += __shfl_xor(p0, 4); p1 += __shfl_xor(p1, 4);
        if (sub == 0) {
            float ir = inv_r[n];
            float wb = warr[n] * ir;
            int g = batch[n];
            atomicAdd(&sm[2 * g + 0], p0 * ir + wb * b3[0]);
            atomicAdd(&sm[2 * g + 1], p1 * ir + wb * b3[1]);
        }
    }
    __syncthreads();
    // skip the zero bins (a block touches only a few graphs)
    for (int i = threadIdx.x; i < outSize; i += blockDim.x) {
        float v = sm[i];
        if (v != 0.f) atomicAdd(&out[i], v);
    }
}

extern "C" void kernel_launch(void* const* d_in, const int* in_sizes, int n_in,
                              void* d_out, int out_size, void* d_ws, size_t ws_size,
                              hipStream_t stream) {
    const float* x     = (const float*)d_in[0];
    const int*   S     = (const int*)d_in[1];
    const int*   R     = (const int*)d_in[2];
    const int*   batch = (const int*)d_in[3];
    const float* W1 = (const float*)d_in[5];
    const float* b1 = (const float*)d_in[6];
    const float* W2 = (const float*)d_in[7];
    const float* b2 = (const float*)d_in[8];
    const float* W3 = (const float*)d_in[9];
    const float* b3 = (const float*)d_in[10];

    int nN = in_sizes[0] / 9;
    int nE = in_sizes[1];
    int nB = (nN + 255) / 256;  // 256-node buckets; requires nB <= NBMAX

    char* ws = (char*)d_ws;
    int*   cur   = (int*)ws;                          // nN
    int*   degR  = cur + nN;                          // nN
    float* inv_s = (float*)(degR + nN);               // nN
    float* inv_r = inv_s + nN;                        // nN
    float* warr  = inv_r + nN;                        // nN
    int*   gCntR = (int*)(warr + nN);                 // NBMAX
    int*   gCntS = gCntR + NBMAX;                     // NBMAX
    int*   csr   = gCntS + NBMAX;                     // nE
    bf16t* xs    = (bf16t*)(csr + nE);                // nN*16 bf16 (3.2 MB)
    bf16t* W2f   = xs + (size_t)nN * 16;              // 8192 bf16 (16 KB)
    char*  regA  = (char*)(W2f + 8192);
    // aliasing (bufR/bufS dead after k_pass2; h1s written by k_h1f afterwards)
    unsigned*      bufR = (unsigned*)regA;                                // NBMAX*BCAP*4 = 10.5 MB
    unsigned char* bufS = (unsigned char*)(bufR + (size_t)NBMAX * BCAP);  // NBMAX*BCAP   = 2.6 MB
    bf16t* h1s = (bf16t*)regA;                        // nN*64 bf16 (12.8 MB)
    float* t   = (float*)(regA + (size_t)NBMAX * BCAP * 5);  // nN*2 fp32 (past both regions)

    const int B = 256;

    // ---- build: fat bucket sort (~250 sort blocks x 512 thr + 2 W2-prep), per-bucket CSR etc. ----
    int nSort = (nE + BKCHUNK - 1) / BKCHUNK;
    if (nSort < 1) nSort = 1;
    hipMemsetAsync(gCntR, 0, 2 * NBMAX * 4, stream);
    k_bucket<<<nSort + 2, 512, 0, stream>>>(S, R, bufR, bufS, gCntR, gCntS, W2, W2f, nE, nB);
    k_pass2<<<nB, B, 0, stream>>>(bufR, bufS, gCntR, gCntS, x, csr, cur, degR,
                                  inv_r, inv_s, xs, nN, nB);

    // ---- layer 1: fused gather + 9->64 dense ----
    k_h1f<<<(nN + 15) / 16, B, 0, stream>>>((const unsigned*)xs, W1, b1, csr, cur, degR,
                                            inv_r, inv_s, h1s, warr, nN);

    // ---- layers 2+3: fused gather + MFMA 64->128->2 (also zeroes d_out) ----
    k_l2f<<<(nN + 15) / 16, 128, 0, stream>>>((const unsigned*)h1s, W2f, b2, W3,
                                              inv_r, inv_s, warr, csr, cur, degR,
                                              t, (float*)d_out, out_size, nN);

    // ---- fused layer-3 aggregation + bias + pooling (8 lanes/node) ----
    k_poolg<<<(nN * 8 + B - 1) / B, B, 0, stream>>>(t, inv_r, warr, b3, csr, cur, degR, batch,
                                                    (float*)d_out, nN, out_size);
}